// Round 8
// baseline (424.094 us; speedup 1.0000x reference)
//
#include <hip/hip_runtime.h>
#include <hip/hip_fp16.h>
#include <math.h>

#define BB 2
#define SS 2048
#define EE 1024
#define HH 16
#define DD 64
#define YAT_EPS 1e-5f
#define RR (BB * HH * SS)   // 65536 attention rows

typedef __attribute__((ext_vector_type(8))) short bf16x8;
typedef __attribute__((ext_vector_type(4))) short short4v;
typedef __attribute__((ext_vector_type(4))) float f32x4;
#define MFMA16(a, b, c) __builtin_amdgcn_mfma_f32_16x16x32_bf16((a), (b), (c), 0, 0, 0)

#if __has_builtin(__builtin_amdgcn_exp2f)
#define EXP2(x) __builtin_amdgcn_exp2f(x)
#else
#define EXP2(x) exp2f(x)
#endif
#if __has_builtin(__builtin_amdgcn_rcpf)
#define RCPF(x) __builtin_amdgcn_rcpf(x)
#else
#define RCPF(x) (1.0f / (x))
#endif

__device__ __forceinline__ unsigned short f2bf(float x) {
    unsigned int u = __float_as_uint(x);
    u += 0x7FFFu + ((u >> 16) & 1u);   // RNE
    return (unsigned short)(u >> 16);
}
__device__ __forceinline__ float bf2f(unsigned short h) {
    return __uint_as_float(((unsigned int)h) << 16);
}

__device__ __forceinline__ void async_ld16(void* lds, const void* g) {
    __builtin_amdgcn_global_load_lds(
        (const __attribute__((address_space(1))) unsigned int*)g,
        (__attribute__((address_space(3))) unsigned int*)lds, 16, 0, 0);
}

// fp32 -> bf16 hi/lo split (grid covers n/4 float4s exactly)
__global__ __launch_bounds__(256) void split_f32(const float* __restrict__ in,
                                                 unsigned short* __restrict__ hi,
                                                 unsigned short* __restrict__ lo,
                                                 int n4) {
    int i = blockIdx.x * 256 + threadIdx.x;
    if (i >= n4) return;
    float4 v = ((const float4*)in)[i];
    ushort4 h, l;
    h.x = f2bf(v.x); l.x = f2bf(v.x - bf2f(h.x));
    h.y = f2bf(v.y); l.y = f2bf(v.y - bf2f(h.y));
    h.z = f2bf(v.z); l.z = f2bf(v.z - bf2f(h.z));
    h.w = f2bf(v.w); l.w = f2bf(v.w - bf2f(h.w));
    ((ushort4*)hi)[i] = h;
    ((ushort4*)lo)[i] = l;
}

// 3-pass (hi/lo) bf16 MFMA GEMM: C[M,N] = A[M,K] @ B[N,K]^T + bias.
// MODE 0: fp32 out + bias (O-projection).
// MODE 1: fused QKV epilogue (N=3072): q/k -> bf16 hi/lo [B,H,S,D] + norms;
//         v -> bf16 [B,H,S,D].
template <int MODE>
__global__ __launch_bounds__(256, 2) void gemm3p(
        const unsigned short* __restrict__ Ahi, const unsigned short* __restrict__ Alo,
        const unsigned short* __restrict__ Bhi, const unsigned short* __restrict__ Blo,
        const float* __restrict__ bq, const float* __restrict__ bk,
        const float* __restrict__ bv,
        float* __restrict__ Cf,
        unsigned short* __restrict__ qhi, unsigned short* __restrict__ qlo,
        unsigned short* __restrict__ khi, unsigned short* __restrict__ klo,
        unsigned short* __restrict__ v_sd,
        float* __restrict__ sqn, float* __restrict__ skn,
        int M, int N, int K) {
    __shared__ __align__(16) unsigned short LA_hi[128 * 32];
    __shared__ __align__(16) unsigned short LA_lo[128 * 32];
    __shared__ __align__(16) unsigned short LB_hi[128 * 32];
    __shared__ __align__(16) unsigned short LB_lo[128 * 32];

    const int t = threadIdx.x;
    const int w = t >> 6, lane = t & 63;
    const int quad = lane >> 4, lr = lane & 15;
    const int wy = w & 1, wx = w >> 1;
    const int m0 = blockIdx.y * 128, n0 = blockIdx.x * 128;

    const unsigned short* gsrc;
    unsigned short* ldst;
    if (w == 0)      { gsrc = Ahi + (size_t)m0 * K; ldst = LA_hi; }
    else if (w == 1) { gsrc = Alo + (size_t)m0 * K; ldst = LA_lo; }
    else if (w == 2) { gsrc = Bhi + (size_t)n0 * K; ldst = LB_hi; }
    else             { gsrc = Blo + (size_t)n0 * K; ldst = LB_lo; }
    const unsigned short* gl = gsrc + (size_t)(lane >> 2) * K + (lane & 3) * 8;

    f32x4 acc[4][4];
    #pragma unroll
    for (int i = 0; i < 4; ++i)
        #pragma unroll
        for (int j = 0; j < 4; ++j)
            acc[i][j] = (f32x4){0.f, 0.f, 0.f, 0.f};

    for (int k0 = 0; k0 < K; k0 += 32) {
        __syncthreads();
        #pragma unroll
        for (int i = 0; i < 8; ++i)
            async_ld16(ldst + i * 512, gl + (size_t)i * 16 * K + k0);
        __syncthreads();
        bf16x8 ah[4], al[4], bh_[4], bl_[4];
        #pragma unroll
        for (int i = 0; i < 4; ++i) {
            ah[i]  = *(const bf16x8*)&LA_hi[(wy * 64 + i * 16 + lr) * 32 + quad * 8];
            al[i]  = *(const bf16x8*)&LA_lo[(wy * 64 + i * 16 + lr) * 32 + quad * 8];
            bh_[i] = *(const bf16x8*)&LB_hi[(wx * 64 + i * 16 + lr) * 32 + quad * 8];
            bl_[i] = *(const bf16x8*)&LB_lo[(wx * 64 + i * 16 + lr) * 32 + quad * 8];
        }
        #pragma unroll
        for (int mg = 0; mg < 4; ++mg)
            #pragma unroll
            for (int ns = 0; ns < 4; ++ns) {
                f32x4 a = acc[mg][ns];
                a = MFMA16(ah[mg], bh_[ns], a);
                a = MFMA16(ah[mg], bl_[ns], a);
                a = MFMA16(al[mg], bh_[ns], a);
                acc[mg][ns] = a;
            }
    }

    const int ng = n0 + wx * 64;
    if (MODE == 0) {
        float bias_v[4];
        #pragma unroll
        for (int ns = 0; ns < 4; ++ns) bias_v[ns] = bq[ng + ns * 16 + lr];
        #pragma unroll
        for (int mg = 0; mg < 4; ++mg)
            #pragma unroll
            for (int r = 0; r < 4; ++r) {
                int m = m0 + wy * 64 + mg * 16 + quad * 4 + r;
                #pragma unroll
                for (int ns = 0; ns < 4; ++ns)
                    Cf[(size_t)m * N + ng + ns * 16 + lr] = acc[mg][ns][r] + bias_v[ns];
            }
    } else {
        const int path = ng >> 10;         // 0=q 1=k 2=v
        const int c = ng & 1023;
        const int h = c >> 6;
        const float* bias = path == 0 ? bq : path == 1 ? bk : bv;
        unsigned short* hi_p = path == 0 ? qhi : khi;
        unsigned short* lo_p = path == 0 ? qlo : klo;
        float* nrm = path == 0 ? sqn : skn;
        float bias_v[4];
        #pragma unroll
        for (int ns = 0; ns < 4; ++ns) bias_v[ns] = bias[c + ns * 16 + lr];
        #pragma unroll
        for (int mg = 0; mg < 4; ++mg)
            #pragma unroll
            for (int r = 0; r < 4; ++r) {
                int m = m0 + wy * 64 + mg * 16 + quad * 4 + r;
                int b = m >> 11, s = m & (SS - 1);
                size_t base = ((size_t)(b * HH + h) * SS + s) * DD;
                float v4[4];
                #pragma unroll
                for (int ns = 0; ns < 4; ++ns) v4[ns] = acc[mg][ns][r] + bias_v[ns];
                if (path < 2) {
                    float pn = v4[0] * v4[0] + v4[1] * v4[1] + v4[2] * v4[2] + v4[3] * v4[3];
                    #pragma unroll
                    for (int off = 1; off < 16; off <<= 1) pn += __shfl_xor(pn, off);
                    if (lr == 0) nrm[(size_t)(b * HH + h) * SS + s] = pn;
                    #pragma unroll
                    for (int ns = 0; ns < 4; ++ns) {
                        unsigned short hv = f2bf(v4[ns]);
                        hi_p[base + ns * 16 + lr] = hv;
                        lo_p[base + ns * 16 + lr] = f2bf(v4[ns] - bf2f(hv));
                    }
                } else {
                    #pragma unroll
                    for (int ns = 0; ns < 4; ++ns)
                        v_sd[base + ns * 16 + lr] = f2bf(v4[ns]);
                }
            }
    }
}

// [bh][s][d] -> [bh][d][s] bf16 transpose, 64x64 LDS tiles
__global__ __launch_bounds__(256) void transpose_v(const unsigned short* __restrict__ v_sd,
                                                   unsigned short* __restrict__ vt) {
    __shared__ unsigned short T[64][65];
    const int t = threadIdx.x;
    const int bh = blockIdx.y, s0 = blockIdx.x * 64;
    {
        int sl = t >> 2, d4 = (t & 3) * 16;
        const unsigned short* src = &v_sd[((size_t)bh * SS + s0 + sl) * DD + d4];
        bf16x8 a = *(const bf16x8*)src;
        bf16x8 b = *(const bf16x8*)(src + 8);
        #pragma unroll
        for (int j = 0; j < 8; ++j) {
            T[sl][d4 + j] = (unsigned short)a[j];
            T[sl][d4 + 8 + j] = (unsigned short)b[j];
        }
    }
    __syncthreads();
    {
        int dl = t >> 2, s4 = (t & 3) * 16;
        bf16x8 a, b;
        #pragma unroll
        for (int j = 0; j < 8; ++j) {
            a[j] = (short)T[s4 + j][dl];
            b[j] = (short)T[s4 + 8 + j][dl];
        }
        unsigned short* dst = &vt[((size_t)bh * DD + dl) * SS + s0 + s4];
        *(bf16x8*)dst = a;
        *(bf16x8*)(dst + 8) = b;
    }
}

// MFMA flash attention, transposed-QK, 2 q-groups/wave, K-SPLIT x2 (blockIdx.z
// picks half of the 32 k-tiles -> 1024 blocks = 4 blocks/CU = 16 waves/CU).
// Emits fp16 partial O + fp32 (m,l) per row; combine_attn merges the halves.
// No fences: short-element LDS stores/reads (same addresses) are ordered by
// dependence analysis; P slices double-buffered on kt parity.
__global__ __launch_bounds__(256, 2) void yat_attn_mfma(
        const unsigned short* __restrict__ qhi, const unsigned short* __restrict__ qlo,
        const unsigned short* __restrict__ khi, const unsigned short* __restrict__ klo,
        const unsigned short* __restrict__ vt,
        const float* __restrict__ sqn, const float* __restrict__ skn,
        const float* __restrict__ alphap,
        __half* __restrict__ Opart, float2* __restrict__ mlpart) {
    __shared__ __align__(16) unsigned short Ps[2][4][2][16 * 72];  // [dbuf][wave][mg]

    const int t = threadIdx.x;
    const int w = t >> 6, lane = t & 63;
    const int quad = lane >> 4, lr = lane & 15;
    const int qt = blockIdx.x, bh = blockIdx.y, z = blockIdx.z;
    const int row0 = qt * 128 + w * 32;
    // log2(e) folded into scale: all score/softmax math in exp2 domain
    const float cscale = powf(sqrtf((float)DD) / log1pf((float)DD), alphap[0])
                         * 1.4426950408889634f;

    // persistent Q fragments (B-operand: lane holds q-col = lr), 2 groups
    bf16x8 qh[2][2], ql[2][2];
    float sqe[2];
    #pragma unroll
    for (int mg = 0; mg < 2; ++mg) {
        #pragma unroll
        for (int kd = 0; kd < 2; ++kd) {
            size_t o = ((size_t)bh * SS + row0 + mg * 16 + lr) * DD + kd * 32 + quad * 8;
            qh[mg][kd] = *(const bf16x8*)&qhi[o];
            ql[mg][kd] = *(const bf16x8*)&qlo[o];
        }
        sqe[mg] = sqn[(size_t)bh * SS + row0 + mg * 16 + lr] + YAT_EPS;
    }

    float m_r[2] = {-INFINITY, -INFINITY}, l_r[2] = {0.f, 0.f};
    f32x4 O[2][4];
    #pragma unroll
    for (int mg = 0; mg < 2; ++mg)
        #pragma unroll
        for (int nd = 0; nd < 4; ++nd) O[mg][nd] = (f32x4){0.f, 0.f, 0.f, 0.f};

    for (int kt = z * 16; kt < z * 16 + 16; ++kt) {
        const int kbase = kt * 64;
        // ---- QK'^T = K.Q^T: A = K frag (lane holds s-row), B = Q frags ----
        f32x4 acc[2][4];
        f32x4 sk4[4];
        #pragma unroll
        for (int st = 0; st < 4; ++st) {
            size_t o = ((size_t)bh * SS + kbase + st * 16 + lr) * DD + quad * 8;
            bf16x8 kh0 = *(const bf16x8*)&khi[o];
            bf16x8 kh1 = *(const bf16x8*)&khi[o + 32];
            bf16x8 kl0 = *(const bf16x8*)&klo[o];
            bf16x8 kl1 = *(const bf16x8*)&klo[o + 32];
            sk4[st] = *(const f32x4*)&skn[(size_t)bh * SS + kbase + st * 16 + quad * 4];
            #pragma unroll
            for (int mg = 0; mg < 2; ++mg) {
                f32x4 a = (f32x4){0.f, 0.f, 0.f, 0.f};
                a = MFMA16(kh0, qh[mg][0], a);
                a = MFMA16(kh1, qh[mg][1], a);
                a = MFMA16(kl0, qh[mg][0], a);
                a = MFMA16(kl1, qh[mg][1], a);
                a = MFMA16(kh0, ql[mg][0], a);
                a = MFMA16(kh1, ql[mg][1], a);
                acc[mg][st] = a;
            }
        }
        // ---- V fragments (shared by both groups) ----
        bf16x8 vf[4][2];
        #pragma unroll
        for (int nd = 0; nd < 4; ++nd)
            #pragma unroll
            for (int kk = 0; kk < 2; ++kk)
                vf[nd][kk] = *(const bf16x8*)&vt[((size_t)bh * DD + nd * 16 + lr) * SS
                                                 + kbase + kk * 32 + quad * 8];
        // ---- per-group softmax + P store + O rescale ----
        #pragma unroll
        for (int mg = 0; mg < 2; ++mg) {
            unsigned short* myP = Ps[kt & 1][w][mg];
            float mx = -INFINITY;
            #pragma unroll
            for (int st = 0; st < 4; ++st)
                #pragma unroll
                for (int r = 0; r < 4; ++r) {
                    float qk = acc[mg][st][r];
                    float d = sqe[mg] + sk4[st][r] - 2.f * qk;
                    float s = qk * qk * cscale * RCPF(d);
                    acc[mg][st][r] = s;
                    mx = fmaxf(mx, s);
                }
            mx = fmaxf(mx, __shfl_xor(mx, 16));
            mx = fmaxf(mx, __shfl_xor(mx, 32));
            float mnew = fmaxf(m_r[mg], mx);
            float aa = EXP2(m_r[mg] - mnew);
            m_r[mg] = mnew;
            float rs = 0.f;
            #pragma unroll
            for (int st = 0; st < 4; ++st)
                #pragma unroll
                for (int r = 0; r < 4; ++r) {
                    float e = EXP2(acc[mg][st][r] - mnew);
                    acc[mg][st][r] = e;
                    rs += e;
                }
            rs += __shfl_xor(rs, 16);
            rs += __shfl_xor(rs, 32);
            l_r[mg] = l_r[mg] * aa + rs;
            #pragma unroll
            for (int st = 0; st < 4; ++st) {
                short4v pv;
                pv[0] = (short)f2bf(acc[mg][st][0]);
                pv[1] = (short)f2bf(acc[mg][st][1]);
                pv[2] = (short)f2bf(acc[mg][st][2]);
                pv[3] = (short)f2bf(acc[mg][st][3]);
                *(short4v*)&myP[lr * 72 + st * 16 + quad * 4] = pv;
            }
            float al_[4];
            #pragma unroll
            for (int r = 0; r < 4; ++r) al_[r] = __shfl(aa, quad * 4 + r);
            #pragma unroll
            for (int nd = 0; nd < 4; ++nd)
                #pragma unroll
                for (int r = 0; r < 4; ++r)
                    O[mg][nd][r] *= al_[r];
        }
        // ---- PV per group: A = P from LDS, B = V^T ----
        #pragma unroll
        for (int mg = 0; mg < 2; ++mg) {
            unsigned short* myP = Ps[kt & 1][w][mg];
            bf16x8 pf[2];
            #pragma unroll
            for (int kk = 0; kk < 2; ++kk)
                pf[kk] = *(const bf16x8*)&myP[lr * 72 + kk * 32 + quad * 8];
            #pragma unroll
            for (int nd = 0; nd < 4; ++nd)
                #pragma unroll
                for (int kk = 0; kk < 2; ++kk)
                    O[mg][nd] = MFMA16(pf[kk], vf[nd][kk], O[mg][nd]);
        }
    }
    // ---- epilogue: write fp16 partial O + (m,l) ----
    #pragma unroll
    for (int mg = 0; mg < 2; ++mg) {
        if (quad == 0)
            mlpart[(size_t)z * RR + (size_t)bh * SS + row0 + mg * 16 + lr] =
                make_float2(m_r[mg], l_r[mg]);
        #pragma unroll
        for (int r = 0; r < 4; ++r) {
            size_t rowg = (size_t)bh * SS + row0 + mg * 16 + quad * 4 + r;
            #pragma unroll
            for (int nd = 0; nd < 4; ++nd)
                Opart[((size_t)z * RR + rowg) * DD + nd * 16 + lr] =
                    __float2half(O[mg][nd][r]);
        }
    }
}

// merge the two K-split halves: standard online-softmax combine, write ctx hi/lo
__global__ __launch_bounds__(256) void combine_attn(
        const __half* __restrict__ Opart, const float2* __restrict__ mlpart,
        unsigned short* __restrict__ ctxhi, unsigned short* __restrict__ ctxlo) {
    int tid = blockIdx.x * 256 + threadIdx.x;
    int row = tid >> 4, c4 = (tid & 15) * 4;
    float2 ml0 = mlpart[row];
    float2 ml1 = mlpart[RR + row];
    float ms = fmaxf(ml0.x, ml1.x);
    float a0 = EXP2(ml0.x - ms), a1 = EXP2(ml1.x - ms);
    float inv = RCPF(ml0.y * a0 + ml1.y * a1);
    a0 *= inv; a1 *= inv;
    const __half* p0 = Opart + (size_t)row * DD + c4;
    const __half* p1 = p0 + (size_t)RR * DD;
    int bh = row >> 11, s = row & (SS - 1);
    int b = bh >> 4, h = bh & 15;
    size_t idx = ((size_t)b * SS + s) * EE + h * DD + c4;
    ushort4 hv, lv;
    unsigned short* hp = (unsigned short*)&hv;
    unsigned short* lp = (unsigned short*)&lv;
    #pragma unroll
    for (int j = 0; j < 4; ++j) {
        float o = __half2float(p0[j]) * a0 + __half2float(p1[j]) * a1;
        unsigned short hh = f2bf(o);
        hp[j] = hh;
        lp[j] = f2bf(o - bf2f(hh));
    }
    *(ushort4*)&ctxhi[idx] = hv;
    *(ushort4*)&ctxlo[idx] = lv;
}

extern "C" void kernel_launch(void* const* d_in, const int* in_sizes, int n_in,
                              void* d_out, int out_size, void* d_ws, size_t ws_size,
                              hipStream_t stream) {
    const float* x     = (const float*)d_in[0];
    const float* Wq    = (const float*)d_in[1];
    const float* bq    = (const float*)d_in[2];
    const float* Wk    = (const float*)d_in[3];
    const float* bk    = (const float*)d_in[4];
    const float* Wv    = (const float*)d_in[5];
    const float* bv    = (const float*)d_in[6];
    const float* Wo    = (const float*)d_in[7];
    const float* bo    = (const float*)d_in[8];
    const float* alpha = (const float*)d_in[9];
    float* out = (float*)d_out;
    char* ws = (char*)d_ws;

    const int M = BB * SS;                 // 4096
    const size_t MB = 1u << 20;
    // layout (MB offsets); aliases safe per pipeline order:
    unsigned short* xhi  = (unsigned short*)(ws + 0 * MB);   // later: ctxhi
    unsigned short* xlo  = (unsigned short*)(ws + 8 * MB);   // later: ctxlo
    unsigned short* Whi  = (unsigned short*)(ws + 16 * MB);  // 6 MB (qkv concat)
    unsigned short* Wlo  = (unsigned short*)(ws + 22 * MB);  // 6 MB
    unsigned short* vt   = (unsigned short*)(ws + 16 * MB);  // 8 MB, reuses dead W
    float2* mlpart       = (float2*)(ws + 24 * MB);          // 1 MB, dead Wlo tail
    unsigned short* Wohi = (unsigned short*)(ws + 28 * MB);
    unsigned short* Wolo = (unsigned short*)(ws + 30 * MB);
    unsigned short* qhi  = (unsigned short*)(ws + 32 * MB);
    unsigned short* qlo  = (unsigned short*)(ws + 40 * MB);
    unsigned short* khi  = (unsigned short*)(ws + 48 * MB);
    unsigned short* klo  = (unsigned short*)(ws + 56 * MB);
    unsigned short* v_sd = (unsigned short*)(ws + 64 * MB);  // dead after transpose
    __half* Opart        = (__half*)(ws + 64 * MB);          // 16 MB (reuses v_sd... )
    float* sqn = (float*)(ws + 80 * MB);
    float* skn = (float*)(ws + 80 * MB + 256 * 1024);
    unsigned short* ctxhi = xhi;
    unsigned short* ctxlo = xlo;
    // NOTE: Opart split0 (64-72MB) overlays v_sd, which is consumed by
    // transpose_v BEFORE yat_attn_mfma writes Opart. split1 at 72-80MB fresh.

    const int nX = M * EE / 4, nW = EE * EE / 4;
    split_f32<<<nX / 256, 256, 0, stream>>>(x, xhi, xlo, nX);
    split_f32<<<nW / 256, 256, 0, stream>>>(Wq, Whi, Wlo, nW);
    split_f32<<<nW / 256, 256, 0, stream>>>(Wk, Whi + (size_t)EE * EE, Wlo + (size_t)EE * EE, nW);
    split_f32<<<nW / 256, 256, 0, stream>>>(Wv, Whi + 2 * (size_t)EE * EE, Wlo + 2 * (size_t)EE * EE, nW);
    split_f32<<<nW / 256, 256, 0, stream>>>(Wo, Wohi, Wolo, nW);

    gemm3p<1><<<dim3(3 * EE / 128, M / 128), 256, 0, stream>>>(
        xhi, xlo, Whi, Wlo, bq, bk, bv, nullptr,
        qhi, qlo, khi, klo, v_sd, sqn, skn, M, 3 * EE, EE);

    transpose_v<<<dim3(SS / 64, BB * HH), 256, 0, stream>>>(v_sd, vt);

    yat_attn_mfma<<<dim3(SS / 128, BB * HH, 2), 256, 0, stream>>>(
        qhi, qlo, khi, klo, vt, sqn, skn, alpha, Opart, mlpart);

    combine_attn<<<RR * 16 / 256, 256, 0, stream>>>(Opart, mlpart, ctxhi, ctxlo);

    gemm3p<0><<<dim3(EE / 128, M / 128), 256, 0, stream>>>(
        ctxhi, ctxlo, Wohi, Wolo, bo, nullptr, nullptr, out,
        nullptr, nullptr, nullptr, nullptr, nullptr, nullptr, nullptr, M, EE, EE);
}

// Round 9
// 385.273 us; speedup vs baseline: 1.1008x; 1.1008x over previous
//
#include <hip/hip_runtime.h>
#include <hip/hip_fp16.h>
#include <math.h>

#define BB 2
#define SS 2048
#define EE 1024
#define HH 16
#define DD 64
#define YAT_EPS 1e-5f
#define RR (BB * HH * SS)   // 65536 attention rows

typedef __attribute__((ext_vector_type(8))) short bf16x8;
typedef __attribute__((ext_vector_type(4))) short short4v;
typedef __attribute__((ext_vector_type(4))) float f32x4;
#define MFMA16(a, b, c) __builtin_amdgcn_mfma_f32_16x16x32_bf16((a), (b), (c), 0, 0, 0)

#if __has_builtin(__builtin_amdgcn_exp2f)
#define EXP2(x) __builtin_amdgcn_exp2f(x)
#else
#define EXP2(x) exp2f(x)
#endif
#if __has_builtin(__builtin_amdgcn_rcpf)
#define RCPF(x) __builtin_amdgcn_rcpf(x)
#else
#define RCPF(x) (1.0f / (x))
#endif

__device__ __forceinline__ unsigned short f2bf(float x) {
    unsigned int u = __float_as_uint(x);
    u += 0x7FFFu + ((u >> 16) & 1u);   // RNE
    return (unsigned short)(u >> 16);
}
__device__ __forceinline__ float bf2f(unsigned short h) {
    return __uint_as_float(((unsigned int)h) << 16);
}

__device__ __forceinline__ void async_ld16(void* lds, const void* g) {
    __builtin_amdgcn_global_load_lds(
        (const __attribute__((address_space(1))) unsigned int*)g,
        (__attribute__((address_space(3))) unsigned int*)lds, 16, 0, 0);
}

// fp32 -> bf16 hi/lo split (grid covers n/4 float4s exactly)
__global__ __launch_bounds__(256) void split_f32(const float* __restrict__ in,
                                                 unsigned short* __restrict__ hi,
                                                 unsigned short* __restrict__ lo,
                                                 int n4) {
    int i = blockIdx.x * 256 + threadIdx.x;
    if (i >= n4) return;
    float4 v = ((const float4*)in)[i];
    ushort4 h, l;
    h.x = f2bf(v.x); l.x = f2bf(v.x - bf2f(h.x));
    h.y = f2bf(v.y); l.y = f2bf(v.y - bf2f(h.y));
    h.z = f2bf(v.z); l.z = f2bf(v.z - bf2f(h.z));
    h.w = f2bf(v.w); l.w = f2bf(v.w - bf2f(h.w));
    ((ushort4*)hi)[i] = h;
    ((ushort4*)lo)[i] = l;
}

// 3-pass (hi/lo) bf16 MFMA GEMM: C[M,N] = A[M,K] @ B[N,K]^T + bias.
// MODE 0: fp32 out + bias (O-projection).
// MODE 1: fused QKV epilogue (N=3072): q/k -> bf16 hi/lo [B,H,S,D] + norms;
//         v -> bf16 [B,H,S,D].
template <int MODE>
__global__ __launch_bounds__(256, 2) void gemm3p(
        const unsigned short* __restrict__ Ahi, const unsigned short* __restrict__ Alo,
        const unsigned short* __restrict__ Bhi, const unsigned short* __restrict__ Blo,
        const float* __restrict__ bq, const float* __restrict__ bk,
        const float* __restrict__ bv,
        float* __restrict__ Cf,
        unsigned short* __restrict__ qhi, unsigned short* __restrict__ qlo,
        unsigned short* __restrict__ khi, unsigned short* __restrict__ klo,
        unsigned short* __restrict__ v_sd,
        float* __restrict__ sqn, float* __restrict__ skn,
        int M, int N, int K) {
    __shared__ __align__(16) unsigned short LA_hi[128 * 32];
    __shared__ __align__(16) unsigned short LA_lo[128 * 32];
    __shared__ __align__(16) unsigned short LB_hi[128 * 32];
    __shared__ __align__(16) unsigned short LB_lo[128 * 32];

    const int t = threadIdx.x;
    const int w = t >> 6, lane = t & 63;
    const int quad = lane >> 4, lr = lane & 15;
    const int wy = w & 1, wx = w >> 1;
    const int m0 = blockIdx.y * 128, n0 = blockIdx.x * 128;

    const unsigned short* gsrc;
    unsigned short* ldst;
    if (w == 0)      { gsrc = Ahi + (size_t)m0 * K; ldst = LA_hi; }
    else if (w == 1) { gsrc = Alo + (size_t)m0 * K; ldst = LA_lo; }
    else if (w == 2) { gsrc = Bhi + (size_t)n0 * K; ldst = LB_hi; }
    else             { gsrc = Blo + (size_t)n0 * K; ldst = LB_lo; }
    const unsigned short* gl = gsrc + (size_t)(lane >> 2) * K + (lane & 3) * 8;

    f32x4 acc[4][4];
    #pragma unroll
    for (int i = 0; i < 4; ++i)
        #pragma unroll
        for (int j = 0; j < 4; ++j)
            acc[i][j] = (f32x4){0.f, 0.f, 0.f, 0.f};

    for (int k0 = 0; k0 < K; k0 += 32) {
        __syncthreads();
        #pragma unroll
        for (int i = 0; i < 8; ++i)
            async_ld16(ldst + i * 512, gl + (size_t)i * 16 * K + k0);
        __syncthreads();
        bf16x8 ah[4], al[4], bh_[4], bl_[4];
        #pragma unroll
        for (int i = 0; i < 4; ++i) {
            ah[i]  = *(const bf16x8*)&LA_hi[(wy * 64 + i * 16 + lr) * 32 + quad * 8];
            al[i]  = *(const bf16x8*)&LA_lo[(wy * 64 + i * 16 + lr) * 32 + quad * 8];
            bh_[i] = *(const bf16x8*)&LB_hi[(wx * 64 + i * 16 + lr) * 32 + quad * 8];
            bl_[i] = *(const bf16x8*)&LB_lo[(wx * 64 + i * 16 + lr) * 32 + quad * 8];
        }
        #pragma unroll
        for (int mg = 0; mg < 4; ++mg)
            #pragma unroll
            for (int ns = 0; ns < 4; ++ns) {
                f32x4 a = acc[mg][ns];
                a = MFMA16(ah[mg], bh_[ns], a);
                a = MFMA16(ah[mg], bl_[ns], a);
                a = MFMA16(al[mg], bh_[ns], a);
                acc[mg][ns] = a;
            }
    }

    const int ng = n0 + wx * 64;
    if (MODE == 0) {
        float bias_v[4];
        #pragma unroll
        for (int ns = 0; ns < 4; ++ns) bias_v[ns] = bq[ng + ns * 16 + lr];
        #pragma unroll
        for (int mg = 0; mg < 4; ++mg)
            #pragma unroll
            for (int r = 0; r < 4; ++r) {
                int m = m0 + wy * 64 + mg * 16 + quad * 4 + r;
                #pragma unroll
                for (int ns = 0; ns < 4; ++ns)
                    Cf[(size_t)m * N + ng + ns * 16 + lr] = acc[mg][ns][r] + bias_v[ns];
            }
    } else {
        const int path = ng >> 10;         // 0=q 1=k 2=v
        const int c = ng & 1023;
        const int h = c >> 6;
        const float* bias = path == 0 ? bq : path == 1 ? bk : bv;
        unsigned short* hi_p = path == 0 ? qhi : khi;
        unsigned short* lo_p = path == 0 ? qlo : klo;
        float* nrm = path == 0 ? sqn : skn;
        float bias_v[4];
        #pragma unroll
        for (int ns = 0; ns < 4; ++ns) bias_v[ns] = bias[c + ns * 16 + lr];
        #pragma unroll
        for (int mg = 0; mg < 4; ++mg)
            #pragma unroll
            for (int r = 0; r < 4; ++r) {
                int m = m0 + wy * 64 + mg * 16 + quad * 4 + r;
                int b = m >> 11, s = m & (SS - 1);
                size_t base = ((size_t)(b * HH + h) * SS + s) * DD;
                float v4[4];
                #pragma unroll
                for (int ns = 0; ns < 4; ++ns) v4[ns] = acc[mg][ns][r] + bias_v[ns];
                if (path < 2) {
                    float pn = v4[0] * v4[0] + v4[1] * v4[1] + v4[2] * v4[2] + v4[3] * v4[3];
                    #pragma unroll
                    for (int off = 1; off < 16; off <<= 1) pn += __shfl_xor(pn, off);
                    if (lr == 0) nrm[(size_t)(b * HH + h) * SS + s] = pn;
                    #pragma unroll
                    for (int ns = 0; ns < 4; ++ns) {
                        unsigned short hv = f2bf(v4[ns]);
                        hi_p[base + ns * 16 + lr] = hv;
                        lo_p[base + ns * 16 + lr] = f2bf(v4[ns] - bf2f(hv));
                    }
                } else {
                    #pragma unroll
                    for (int ns = 0; ns < 4; ++ns)
                        v_sd[base + ns * 16 + lr] = f2bf(v4[ns]);
                }
            }
    }
}

// [bh][s][d] -> [bh][d][s] bf16 transpose, 64x64 LDS tiles
__global__ __launch_bounds__(256) void transpose_v(const unsigned short* __restrict__ v_sd,
                                                   unsigned short* __restrict__ vt) {
    __shared__ unsigned short T[64][65];
    const int t = threadIdx.x;
    const int bh = blockIdx.y, s0 = blockIdx.x * 64;
    {
        int sl = t >> 2, d4 = (t & 3) * 16;
        const unsigned short* src = &v_sd[((size_t)bh * SS + s0 + sl) * DD + d4];
        bf16x8 a = *(const bf16x8*)src;
        bf16x8 b = *(const bf16x8*)(src + 8);
        #pragma unroll
        for (int j = 0; j < 8; ++j) {
            T[sl][d4 + j] = (unsigned short)a[j];
            T[sl][d4 + 8 + j] = (unsigned short)b[j];
        }
    }
    __syncthreads();
    {
        int dl = t >> 2, s4 = (t & 3) * 16;
        bf16x8 a, b;
        #pragma unroll
        for (int j = 0; j < 8; ++j) {
            a[j] = (short)T[s4 + j][dl];
            b[j] = (short)T[s4 + 8 + j][dl];
        }
        unsigned short* dst = &vt[((size_t)bh * DD + dl) * SS + s0 + s4];
        *(bf16x8*)dst = a;
        *(bf16x8*)(dst + 8) = b;
    }
}

// MFMA flash attention v3: transposed-QK, 2 q-groups/wave, K-split x2, and
// LDS-STAGED K tiles (hi+lo, 16KB/tile) with double-buffered async
// global_load_lds prefetch: tile i+1's loads issue right after the barrier
// and stay in flight across tile i's compute (drained by the next
// __syncthreads' vmcnt(0)). XOR-swizzled 16B chunks keep ds_read_b128
// bank-balanced while preserving the lane-contiguous async-write pattern.
// K frags read from LDS just-in-time -> register peak ~140 -> (256,3)
// allows 3 waves/SIMD; LDS 50.2KB -> 3 blocks/CU.
__global__ __launch_bounds__(256, 3) void yat_attn_mfma(
        const unsigned short* __restrict__ qhi, const unsigned short* __restrict__ qlo,
        const unsigned short* __restrict__ khi, const unsigned short* __restrict__ klo,
        const unsigned short* __restrict__ vt,
        const float* __restrict__ sqn, const float* __restrict__ skn,
        const float* __restrict__ alphap,
        __half* __restrict__ Opart, float2* __restrict__ mlpart) {
    __shared__ __align__(16) unsigned short Ks[2][8192];        // [dbuf][kh(4096)|kl(4096)] 32KB
    __shared__ __align__(16) unsigned short Ps[4][2][16 * 68];  // [wave][grp] 17.4KB

    const int t = threadIdx.x;
    const int w = t >> 6, lane = t & 63;
    const int quad = lane >> 4, lr = lane & 15;
    const int qt = blockIdx.x, bh = blockIdx.y, z = blockIdx.z;
    const int row0 = qt * 128 + w * 32;
    // log2(e) folded into scale: all score/softmax math in exp2 domain
    const float cscale = powf(sqrtf((float)DD) / log1pf((float)DD), alphap[0])
                         * 1.4426950408889634f;

    // persistent Q fragments (B-operand: lane holds q-col = lr), 2 groups
    bf16x8 qh[2][2], ql[2][2];
    float sqe[2];
    #pragma unroll
    for (int mg = 0; mg < 2; ++mg) {
        #pragma unroll
        for (int kd = 0; kd < 2; ++kd) {
            size_t o = ((size_t)bh * SS + row0 + mg * 16 + lr) * DD + kd * 32 + quad * 8;
            qh[mg][kd] = *(const bf16x8*)&qhi[o];
            ql[mg][kd] = *(const bf16x8*)&qlo[o];
        }
        sqe[mg] = sqn[(size_t)bh * SS + row0 + mg * 16 + lr] + YAT_EPS;
    }

    // staging geometry: wave w stages rows [w*16, w*16+16) of kh and kl.
    // lane l covers (row = 8*i + l/8, lds-chunk = l%8); global chunk is
    // XOR-swizzled so lds position c' holds global chunk c'^(row&7).
    const int lrow = lane >> 3;
    const int lofs = lrow * 64 + (((lane & 7) ^ (lrow & 7)) << 3);  // shorts in 8-row slab

    float m_r[2] = {-INFINITY, -INFINITY}, l_r[2] = {0.f, 0.f};
    f32x4 O[2][4];
    #pragma unroll
    for (int mg = 0; mg < 2; ++mg)
        #pragma unroll
        for (int nd = 0; nd < 4; ++nd) O[mg][nd] = (f32x4){0.f, 0.f, 0.f, 0.f};

    const int kt0 = z * 16;
    // prologue: stage tile 0 into buf 0
    {
        const size_t gbase = ((size_t)bh * SS + kt0 * 64 + w * 16) * 64 + lofs;
        #pragma unroll
        for (int i2 = 0; i2 < 2; ++i2) {
            async_ld16(&Ks[0][w * 1024 + i2 * 512],        khi + gbase + i2 * 512);
            async_ld16(&Ks[0][4096 + w * 1024 + i2 * 512], klo + gbase + i2 * 512);
        }
    }

    for (int it = 0; it < 16; ++it) {
        const int kt = kt0 + it;
        const int p = it & 1;
        const int kbase = kt * 64;
        __syncthreads();   // drains async stage of buf[p]; buf[p^1] free (prev compute done)
        if (it < 15) {     // prefetch next tile into buf[p^1]
            const size_t gbase = ((size_t)bh * SS + (kt + 1) * 64 + w * 16) * 64 + lofs;
            #pragma unroll
            for (int i2 = 0; i2 < 2; ++i2) {
                async_ld16(&Ks[p ^ 1][w * 1024 + i2 * 512],        khi + gbase + i2 * 512);
                async_ld16(&Ks[p ^ 1][4096 + w * 1024 + i2 * 512], klo + gbase + i2 * 512);
            }
        }
        // ---- QK'^T = K.Q^T from LDS: A = K frag (lane holds s-row) ----
        f32x4 acc[2][4];
        f32x4 sk4[4];
        const unsigned short* kb = Ks[p];
        const int sw = lr & 7;
        #pragma unroll
        for (int st = 0; st < 4; ++st) {
            const int rbase = (st * 16 + lr) * 64;
            bf16x8 kh0 = *(const bf16x8*)&kb[rbase + ((quad    ) ^ sw) * 8];
            bf16x8 kh1 = *(const bf16x8*)&kb[rbase + ((quad + 4) ^ sw) * 8];
            bf16x8 kl0 = *(const bf16x8*)&kb[4096 + rbase + ((quad    ) ^ sw) * 8];
            bf16x8 kl1 = *(const bf16x8*)&kb[4096 + rbase + ((quad + 4) ^ sw) * 8];
            sk4[st] = *(const f32x4*)&skn[(size_t)bh * SS + kbase + st * 16 + quad * 4];
            #pragma unroll
            for (int mg = 0; mg < 2; ++mg) {
                f32x4 a = (f32x4){0.f, 0.f, 0.f, 0.f};
                a = MFMA16(kh0, qh[mg][0], a);
                a = MFMA16(kh1, qh[mg][1], a);
                a = MFMA16(kl0, qh[mg][0], a);
                a = MFMA16(kl1, qh[mg][1], a);
                a = MFMA16(kh0, ql[mg][0], a);
                a = MFMA16(kh1, ql[mg][1], a);
                acc[mg][st] = a;
            }
        }
        // ---- V fragments (global; issue early to overlap softmax VALU) ----
        bf16x8 vf[4][2];
        #pragma unroll
        for (int nd = 0; nd < 4; ++nd)
            #pragma unroll
            for (int kk = 0; kk < 2; ++kk)
                vf[nd][kk] = *(const bf16x8*)&vt[((size_t)bh * DD + nd * 16 + lr) * SS
                                                 + kbase + kk * 32 + quad * 8];
        // ---- per-group softmax + P store + O rescale ----
        #pragma unroll
        for (int mg = 0; mg < 2; ++mg) {
            unsigned short* myP = Ps[w][mg];
            float mx = -INFINITY;
            #pragma unroll
            for (int st = 0; st < 4; ++st)
                #pragma unroll
                for (int r = 0; r < 4; ++r) {
                    float qk = acc[mg][st][r];
                    float d = sqe[mg] + sk4[st][r] - 2.f * qk;
                    float s = qk * qk * cscale * RCPF(d);
                    acc[mg][st][r] = s;
                    mx = fmaxf(mx, s);
                }
            mx = fmaxf(mx, __shfl_xor(mx, 16));
            mx = fmaxf(mx, __shfl_xor(mx, 32));
            float mnew = fmaxf(m_r[mg], mx);
            float aa = EXP2(m_r[mg] - mnew);
            m_r[mg] = mnew;
            float rs = 0.f;
            #pragma unroll
            for (int st = 0; st < 4; ++st)
                #pragma unroll
                for (int r = 0; r < 4; ++r) {
                    float e = EXP2(acc[mg][st][r] - mnew);
                    acc[mg][st][r] = e;
                    rs += e;
                }
            rs += __shfl_xor(rs, 16);
            rs += __shfl_xor(rs, 32);
            l_r[mg] = l_r[mg] * aa + rs;
            #pragma unroll
            for (int st = 0; st < 4; ++st) {
                short4v pv;
                pv[0] = (short)f2bf(acc[mg][st][0]);
                pv[1] = (short)f2bf(acc[mg][st][1]);
                pv[2] = (short)f2bf(acc[mg][st][2]);
                pv[3] = (short)f2bf(acc[mg][st][3]);
                *(short4v*)&myP[lr * 68 + st * 16 + quad * 4] = pv;
            }
            float al_[4];
            #pragma unroll
            for (int r = 0; r < 4; ++r) al_[r] = __shfl(aa, quad * 4 + r);
            #pragma unroll
            for (int nd = 0; nd < 4; ++nd)
                #pragma unroll
                for (int r = 0; r < 4; ++r)
                    O[mg][nd][r] *= al_[r];
        }
        // ---- PV per group: A = P from LDS, B = V^T ----
        #pragma unroll
        for (int mg = 0; mg < 2; ++mg) {
            unsigned short* myP = Ps[w][mg];
            bf16x8 pf[2];
            #pragma unroll
            for (int kk = 0; kk < 2; ++kk)
                pf[kk] = *(const bf16x8*)&myP[lr * 68 + kk * 32 + quad * 8];
            #pragma unroll
            for (int nd = 0; nd < 4; ++nd)
                #pragma unroll
                for (int kk = 0; kk < 2; ++kk)
                    O[mg][nd] = MFMA16(pf[kk], vf[nd][kk], O[mg][nd]);
        }
    }
    // ---- epilogue: write fp16 partial O + (m,l) ----
    #pragma unroll
    for (int mg = 0; mg < 2; ++mg) {
        if (quad == 0)
            mlpart[(size_t)z * RR + (size_t)bh * SS + row0 + mg * 16 + lr] =
                make_float2(m_r[mg], l_r[mg]);
        #pragma unroll
        for (int r = 0; r < 4; ++r) {
            size_t rowg = (size_t)bh * SS + row0 + mg * 16 + quad * 4 + r;
            #pragma unroll
            for (int nd = 0; nd < 4; ++nd)
                Opart[((size_t)z * RR + rowg) * DD + nd * 16 + lr] =
                    __float2half(O[mg][nd][r]);
        }
    }
}

// merge the two K-split halves: standard online-softmax combine, write ctx hi/lo
__global__ __launch_bounds__(256) void combine_attn(
        const __half* __restrict__ Opart, const float2* __restrict__ mlpart,
        unsigned short* __restrict__ ctxhi, unsigned short* __restrict__ ctxlo) {
    int tid = blockIdx.x * 256 + threadIdx.x;
    int row = tid >> 4, c4 = (tid & 15) * 4;
    float2 ml0 = mlpart[row];
    float2 ml1 = mlpart[RR + row];
    float ms = fmaxf(ml0.x, ml1.x);
    float a0 = EXP2(ml0.x - ms), a1 = EXP2(ml1.x - ms);
    float inv = RCPF(ml0.y * a0 + ml1.y * a1);
    a0 *= inv; a1 *= inv;
    const __half* p0 = Opart + (size_t)row * DD + c4;
    const __half* p1 = p0 + (size_t)RR * DD;
    int bh = row >> 11, s = row & (SS - 1);
    int b = bh >> 4, h = bh & 15;
    size_t idx = ((size_t)b * SS + s) * EE + h * DD + c4;
    ushort4 hv, lv;
    unsigned short* hp = (unsigned short*)&hv;
    unsigned short* lp = (unsigned short*)&lv;
    #pragma unroll
    for (int j = 0; j < 4; ++j) {
        float o = __half2float(p0[j]) * a0 + __half2float(p1[j]) * a1;
        unsigned short hh = f2bf(o);
        hp[j] = hh;
        lp[j] = f2bf(o - bf2f(hh));
    }
    *(ushort4*)&ctxhi[idx] = hv;
    *(ushort4*)&ctxlo[idx] = lv;
}

extern "C" void kernel_launch(void* const* d_in, const int* in_sizes, int n_in,
                              void* d_out, int out_size, void* d_ws, size_t ws_size,
                              hipStream_t stream) {
    const float* x     = (const float*)d_in[0];
    const float* Wq    = (const float*)d_in[1];
    const float* bq    = (const float*)d_in[2];
    const float* Wk    = (const float*)d_in[3];
    const float* bk    = (const float*)d_in[4];
    const float* Wv    = (const float*)d_in[5];
    const float* bv    = (const float*)d_in[6];
    const float* Wo    = (const float*)d_in[7];
    const float* bo    = (const float*)d_in[8];
    const float* alpha = (const float*)d_in[9];
    float* out = (float*)d_out;
    char* ws = (char*)d_ws;

    const int M = BB * SS;                 // 4096
    const size_t MB = 1u << 20;
    // layout (MB offsets); aliases safe per pipeline order:
    unsigned short* xhi  = (unsigned short*)(ws + 0 * MB);   // later: ctxhi
    unsigned short* xlo  = (unsigned short*)(ws + 8 * MB);   // later: ctxlo
    unsigned short* Whi  = (unsigned short*)(ws + 16 * MB);  // 6 MB (qkv concat)
    unsigned short* Wlo  = (unsigned short*)(ws + 22 * MB);  // 6 MB
    unsigned short* vt   = (unsigned short*)(ws + 16 * MB);  // 8 MB, reuses dead W
    float2* mlpart       = (float2*)(ws + 24 * MB);          // 1 MB, dead Wlo tail
    unsigned short* Wohi = (unsigned short*)(ws + 28 * MB);
    unsigned short* Wolo = (unsigned short*)(ws + 30 * MB);
    unsigned short* qhi  = (unsigned short*)(ws + 32 * MB);
    unsigned short* qlo  = (unsigned short*)(ws + 40 * MB);
    unsigned short* khi  = (unsigned short*)(ws + 48 * MB);
    unsigned short* klo  = (unsigned short*)(ws + 56 * MB);
    unsigned short* v_sd = (unsigned short*)(ws + 64 * MB);  // dead after transpose
    __half* Opart        = (__half*)(ws + 64 * MB);          // 16 MB (reuses v_sd)
    float* sqn = (float*)(ws + 80 * MB);
    float* skn = (float*)(ws + 80 * MB + 256 * 1024);
    unsigned short* ctxhi = xhi;
    unsigned short* ctxlo = xlo;

    const int nX = M * EE / 4, nW = EE * EE / 4;
    split_f32<<<nX / 256, 256, 0, stream>>>(x, xhi, xlo, nX);
    split_f32<<<nW / 256, 256, 0, stream>>>(Wq, Whi, Wlo, nW);
    split_f32<<<nW / 256, 256, 0, stream>>>(Wk, Whi + (size_t)EE * EE, Wlo + (size_t)EE * EE, nW);
    split_f32<<<nW / 256, 256, 0, stream>>>(Wv, Whi + 2 * (size_t)EE * EE, Wlo + 2 * (size_t)EE * EE, nW);
    split_f32<<<nW / 256, 256, 0, stream>>>(Wo, Wohi, Wolo, nW);

    gemm3p<1><<<dim3(3 * EE / 128, M / 128), 256, 0, stream>>>(
        xhi, xlo, Whi, Wlo, bq, bk, bv, nullptr,
        qhi, qlo, khi, klo, v_sd, sqn, skn, M, 3 * EE, EE);

    transpose_v<<<dim3(SS / 64, BB * HH), 256, 0, stream>>>(v_sd, vt);

    yat_attn_mfma<<<dim3(SS / 128, BB * HH, 2), 256, 0, stream>>>(
        qhi, qlo, khi, klo, vt, sqn, skn, alpha, Opart, mlpart);

    combine_attn<<<RR * 16 / 256, 256, 0, stream>>>(Opart, mlpart, ctxhi, ctxlo);

    gemm3p<0><<<dim3(EE / 128, M / 128), 256, 0, stream>>>(
        ctxhi, ctxlo, Wohi, Wolo, bo, nullptr, nullptr, out,
        nullptr, nullptr, nullptr, nullptr, nullptr, nullptr, nullptr, M, EE, EE);
}

// Round 10
// 381.548 us; speedup vs baseline: 1.1115x; 1.0098x over previous
//
#include <hip/hip_runtime.h>
#include <hip/hip_fp16.h>
#include <math.h>

#define BB 2
#define SS 2048
#define EE 1024
#define HH 16
#define DD 64
#define YAT_EPS 1e-5f
#define RR (BB * HH * SS)   // 65536 attention rows

typedef __attribute__((ext_vector_type(8))) short bf16x8;
typedef __attribute__((ext_vector_type(4))) short short4v;
typedef __attribute__((ext_vector_type(4))) float f32x4;
#define MFMA16(a, b, c) __builtin_amdgcn_mfma_f32_16x16x32_bf16((a), (b), (c), 0, 0, 0)

#if __has_builtin(__builtin_amdgcn_exp2f)
#define EXP2(x) __builtin_amdgcn_exp2f(x)
#else
#define EXP2(x) exp2f(x)
#endif
#if __has_builtin(__builtin_amdgcn_rcpf)
#define RCPF(x) __builtin_amdgcn_rcpf(x)
#else
#define RCPF(x) (1.0f / (x))
#endif

__device__ __forceinline__ unsigned short f2bf(float x) {
    unsigned int u = __float_as_uint(x);
    u += 0x7FFFu + ((u >> 16) & 1u);   // RNE
    return (unsigned short)(u >> 16);
}
__device__ __forceinline__ float bf2f(unsigned short h) {
    return __uint_as_float(((unsigned int)h) << 16);
}

__device__ __forceinline__ void async_ld16(void* lds, const void* g) {
    __builtin_amdgcn_global_load_lds(
        (const __attribute__((address_space(1))) unsigned int*)g,
        (__attribute__((address_space(3))) unsigned int*)lds, 16, 0, 0);
}

// fp32 -> bf16 hi/lo split (grid covers n/4 float4s exactly)
__global__ __launch_bounds__(256) void split_f32(const float* __restrict__ in,
                                                 unsigned short* __restrict__ hi,
                                                 unsigned short* __restrict__ lo,
                                                 int n4) {
    int i = blockIdx.x * 256 + threadIdx.x;
    if (i >= n4) return;
    float4 v = ((const float4*)in)[i];
    ushort4 h, l;
    h.x = f2bf(v.x); l.x = f2bf(v.x - bf2f(h.x));
    h.y = f2bf(v.y); l.y = f2bf(v.y - bf2f(h.y));
    h.z = f2bf(v.z); l.z = f2bf(v.z - bf2f(h.z));
    h.w = f2bf(v.w); l.w = f2bf(v.w - bf2f(h.w));
    ((ushort4*)hi)[i] = h;
    ((ushort4*)lo)[i] = l;
}

// fused hi/lo split of the four EExEE weight matrices (blockIdx.y selects)
__global__ __launch_bounds__(256) void split_w4(
        const float* __restrict__ Wq, const float* __restrict__ Wk,
        const float* __restrict__ Wv, const float* __restrict__ Wo,
        unsigned short* __restrict__ Whi, unsigned short* __restrict__ Wlo,
        unsigned short* __restrict__ Wohi, unsigned short* __restrict__ Wolo) {
    int i = blockIdx.x * 256 + threadIdx.x;      // < EE*EE/4
    int y = blockIdx.y;
    const float* src = y == 0 ? Wq : y == 1 ? Wk : y == 2 ? Wv : Wo;
    unsigned short* hi = y < 3 ? Whi + (size_t)y * EE * EE : Wohi;
    unsigned short* lo = y < 3 ? Wlo + (size_t)y * EE * EE : Wolo;
    float4 v = ((const float4*)src)[i];
    ushort4 h, l;
    h.x = f2bf(v.x); l.x = f2bf(v.x - bf2f(h.x));
    h.y = f2bf(v.y); l.y = f2bf(v.y - bf2f(h.y));
    h.z = f2bf(v.z); l.z = f2bf(v.z - bf2f(h.z));
    h.w = f2bf(v.w); l.w = f2bf(v.w - bf2f(h.w));
    ((ushort4*)hi)[i] = h;
    ((ushort4*)lo)[i] = l;
}

// 3-pass (hi/lo) bf16 MFMA GEMM: C[M,N] = A[M,K] @ B[N,K]^T + bias.
// MODE 0: fp32 out + bias (O-projection).
// MODE 1: fused QKV epilogue (N=3072): q/k -> bf16 hi/lo [B,H,S,D] + norms;
//         v -> bf16 [B,H,S,D].
template <int MODE>
__global__ __launch_bounds__(256, 2) void gemm3p(
        const unsigned short* __restrict__ Ahi, const unsigned short* __restrict__ Alo,
        const unsigned short* __restrict__ Bhi, const unsigned short* __restrict__ Blo,
        const float* __restrict__ bq, const float* __restrict__ bk,
        const float* __restrict__ bv,
        float* __restrict__ Cf,
        unsigned short* __restrict__ qhi, unsigned short* __restrict__ qlo,
        unsigned short* __restrict__ khi, unsigned short* __restrict__ klo,
        unsigned short* __restrict__ v_sd,
        float* __restrict__ sqn, float* __restrict__ skn,
        int M, int N, int K) {
    __shared__ __align__(16) unsigned short LA_hi[128 * 32];
    __shared__ __align__(16) unsigned short LA_lo[128 * 32];
    __shared__ __align__(16) unsigned short LB_hi[128 * 32];
    __shared__ __align__(16) unsigned short LB_lo[128 * 32];

    const int t = threadIdx.x;
    const int w = t >> 6, lane = t & 63;
    const int quad = lane >> 4, lr = lane & 15;
    const int wy = w & 1, wx = w >> 1;
    const int m0 = blockIdx.y * 128, n0 = blockIdx.x * 128;

    const unsigned short* gsrc;
    unsigned short* ldst;
    if (w == 0)      { gsrc = Ahi + (size_t)m0 * K; ldst = LA_hi; }
    else if (w == 1) { gsrc = Alo + (size_t)m0 * K; ldst = LA_lo; }
    else if (w == 2) { gsrc = Bhi + (size_t)n0 * K; ldst = LB_hi; }
    else             { gsrc = Blo + (size_t)n0 * K; ldst = LB_lo; }
    const unsigned short* gl = gsrc + (size_t)(lane >> 2) * K + (lane & 3) * 8;

    f32x4 acc[4][4];
    #pragma unroll
    for (int i = 0; i < 4; ++i)
        #pragma unroll
        for (int j = 0; j < 4; ++j)
            acc[i][j] = (f32x4){0.f, 0.f, 0.f, 0.f};

    for (int k0 = 0; k0 < K; k0 += 32) {
        __syncthreads();
        #pragma unroll
        for (int i = 0; i < 8; ++i)
            async_ld16(ldst + i * 512, gl + (size_t)i * 16 * K + k0);
        __syncthreads();
        bf16x8 ah[4], al[4], bh_[4], bl_[4];
        #pragma unroll
        for (int i = 0; i < 4; ++i) {
            ah[i]  = *(const bf16x8*)&LA_hi[(wy * 64 + i * 16 + lr) * 32 + quad * 8];
            al[i]  = *(const bf16x8*)&LA_lo[(wy * 64 + i * 16 + lr) * 32 + quad * 8];
            bh_[i] = *(const bf16x8*)&LB_hi[(wx * 64 + i * 16 + lr) * 32 + quad * 8];
            bl_[i] = *(const bf16x8*)&LB_lo[(wx * 64 + i * 16 + lr) * 32 + quad * 8];
        }
        #pragma unroll
        for (int mg = 0; mg < 4; ++mg)
            #pragma unroll
            for (int ns = 0; ns < 4; ++ns) {
                f32x4 a = acc[mg][ns];
                a = MFMA16(ah[mg], bh_[ns], a);
                a = MFMA16(ah[mg], bl_[ns], a);
                a = MFMA16(al[mg], bh_[ns], a);
                acc[mg][ns] = a;
            }
    }

    const int ng = n0 + wx * 64;
    if (MODE == 0) {
        float bias_v[4];
        #pragma unroll
        for (int ns = 0; ns < 4; ++ns) bias_v[ns] = bq[ng + ns * 16 + lr];
        #pragma unroll
        for (int mg = 0; mg < 4; ++mg)
            #pragma unroll
            for (int r = 0; r < 4; ++r) {
                int m = m0 + wy * 64 + mg * 16 + quad * 4 + r;
                #pragma unroll
                for (int ns = 0; ns < 4; ++ns)
                    Cf[(size_t)m * N + ng + ns * 16 + lr] = acc[mg][ns][r] + bias_v[ns];
            }
    } else {
        const int path = ng >> 10;         // 0=q 1=k 2=v
        const int c = ng & 1023;
        const int h = c >> 6;
        const float* bias = path == 0 ? bq : path == 1 ? bk : bv;
        unsigned short* hi_p = path == 0 ? qhi : khi;
        unsigned short* lo_p = path == 0 ? qlo : klo;
        float* nrm = path == 0 ? sqn : skn;
        float bias_v[4];
        #pragma unroll
        for (int ns = 0; ns < 4; ++ns) bias_v[ns] = bias[c + ns * 16 + lr];
        #pragma unroll
        for (int mg = 0; mg < 4; ++mg)
            #pragma unroll
            for (int r = 0; r < 4; ++r) {
                int m = m0 + wy * 64 + mg * 16 + quad * 4 + r;
                int b = m >> 11, s = m & (SS - 1);
                size_t base = ((size_t)(b * HH + h) * SS + s) * DD;
                float v4[4];
                #pragma unroll
                for (int ns = 0; ns < 4; ++ns) v4[ns] = acc[mg][ns][r] + bias_v[ns];
                if (path < 2) {
                    float pn = v4[0] * v4[0] + v4[1] * v4[1] + v4[2] * v4[2] + v4[3] * v4[3];
                    #pragma unroll
                    for (int off = 1; off < 16; off <<= 1) pn += __shfl_xor(pn, off);
                    if (lr == 0) nrm[(size_t)(b * HH + h) * SS + s] = pn;
                    #pragma unroll
                    for (int ns = 0; ns < 4; ++ns) {
                        unsigned short hv = f2bf(v4[ns]);
                        hi_p[base + ns * 16 + lr] = hv;
                        lo_p[base + ns * 16 + lr] = f2bf(v4[ns] - bf2f(hv));
                    }
                } else {
                    #pragma unroll
                    for (int ns = 0; ns < 4; ++ns)
                        v_sd[base + ns * 16 + lr] = f2bf(v4[ns]);
                }
            }
    }
}

// [bh][s][d] -> [bh][d][s] bf16 transpose, 64x64 LDS tiles
__global__ __launch_bounds__(256) void transpose_v(const unsigned short* __restrict__ v_sd,
                                                   unsigned short* __restrict__ vt) {
    __shared__ unsigned short T[64][65];
    const int t = threadIdx.x;
    const int bh = blockIdx.y, s0 = blockIdx.x * 64;
    {
        int sl = t >> 2, d4 = (t & 3) * 16;
        const unsigned short* src = &v_sd[((size_t)bh * SS + s0 + sl) * DD + d4];
        bf16x8 a = *(const bf16x8*)src;
        bf16x8 b = *(const bf16x8*)(src + 8);
        #pragma unroll
        for (int j = 0; j < 8; ++j) {
            T[sl][d4 + j] = (unsigned short)a[j];
            T[sl][d4 + 8 + j] = (unsigned short)b[j];
        }
    }
    __syncthreads();
    {
        int dl = t >> 2, s4 = (t & 3) * 16;
        bf16x8 a, b;
        #pragma unroll
        for (int j = 0; j < 8; ++j) {
            a[j] = (short)T[s4 + j][dl];
            b[j] = (short)T[s4 + 8 + j][dl];
        }
        unsigned short* dst = &vt[((size_t)bh * DD + dl) * SS + s0 + s4];
        *(bf16x8*)dst = a;
        *(bf16x8*)(dst + 8) = b;
    }
}

// MFMA flash attention v4: 1 q-group per wave (64 q-rows/block). K staged in
// LDS (round-9 structure: double-buffered async global_load_lds, XOR-swizzled
// chunks, 0 bank conflicts), so the 2nd q-group's register cost (~48 regs of
// Q/acc/O state) no longer buys global-traffic amortization — dropping it cuts
// unified VGPR+AGPR from ~180 to ~140 and unlocks 3 waves/SIMD (3 blocks/CU).
__global__ __launch_bounds__(256, 3) void yat_attn_mfma(
        const unsigned short* __restrict__ qhi, const unsigned short* __restrict__ qlo,
        const unsigned short* __restrict__ khi, const unsigned short* __restrict__ klo,
        const unsigned short* __restrict__ vt,
        const float* __restrict__ sqn, const float* __restrict__ skn,
        const float* __restrict__ alphap,
        __half* __restrict__ Opart, float2* __restrict__ mlpart) {
    __shared__ __align__(16) unsigned short Ks[2][8192];     // [dbuf][kh|kl] 32KB
    __shared__ __align__(16) unsigned short Ps[2][4][16 * 68];  // [dbuf][wave] 17.4KB

    const int t = threadIdx.x;
    const int w = t >> 6, lane = t & 63;
    const int quad = lane >> 4, lr = lane & 15;
    const int qt = blockIdx.x, bh = blockIdx.y, z = blockIdx.z;
    const int row0 = qt * 64 + w * 16;
    // log2(e) folded into scale: all score/softmax math in exp2 domain
    const float cscale = powf(sqrtf((float)DD) / log1pf((float)DD), alphap[0])
                         * 1.4426950408889634f;

    // persistent Q fragments (B-operand: lane holds q-col = lr)
    bf16x8 qh[2], ql[2];
    #pragma unroll
    for (int kd = 0; kd < 2; ++kd) {
        size_t o = ((size_t)bh * SS + row0 + lr) * DD + kd * 32 + quad * 8;
        qh[kd] = *(const bf16x8*)&qhi[o];
        ql[kd] = *(const bf16x8*)&qlo[o];
    }
    const float sqe = sqn[(size_t)bh * SS + row0 + lr] + YAT_EPS;

    // staging geometry: wave w stages rows [w*16, w*16+16) of kh and kl.
    // lane l covers (row = 8*i + l/8, lds-chunk = l%8); global chunk is
    // XOR-swizzled so lds position c' holds global chunk c'^(row&7).
    const int lrow = lane >> 3;
    const int lofs = lrow * 64 + (((lane & 7) ^ (lrow & 7)) << 3);

    float m_r = -INFINITY, l_r = 0.f;
    f32x4 O[4];
    #pragma unroll
    for (int nd = 0; nd < 4; ++nd) O[nd] = (f32x4){0.f, 0.f, 0.f, 0.f};

    const int kt0 = z * 16;
    // prologue: stage tile 0 into buf 0
    {
        const size_t gbase = ((size_t)bh * SS + kt0 * 64 + w * 16) * 64 + lofs;
        #pragma unroll
        for (int i2 = 0; i2 < 2; ++i2) {
            async_ld16(&Ks[0][w * 1024 + i2 * 512],        khi + gbase + i2 * 512);
            async_ld16(&Ks[0][4096 + w * 1024 + i2 * 512], klo + gbase + i2 * 512);
        }
    }

    for (int it = 0; it < 16; ++it) {
        const int kt = kt0 + it;
        const int p = it & 1;
        const int kbase = kt * 64;
        __syncthreads();   // drains async stage of buf[p]; buf[p^1] free
        if (it < 15) {     // prefetch next tile into buf[p^1]
            const size_t gbase = ((size_t)bh * SS + (kt + 1) * 64 + w * 16) * 64 + lofs;
            #pragma unroll
            for (int i2 = 0; i2 < 2; ++i2) {
                async_ld16(&Ks[p ^ 1][w * 1024 + i2 * 512],        khi + gbase + i2 * 512);
                async_ld16(&Ks[p ^ 1][4096 + w * 1024 + i2 * 512], klo + gbase + i2 * 512);
            }
        }
        // ---- QK'^T = K.Q^T from LDS: A = K frag (lane holds s-row) ----
        f32x4 acc[4];
        f32x4 sk4[4];
        const unsigned short* kb = Ks[p];
        const int sw = lr & 7;
        #pragma unroll
        for (int st = 0; st < 4; ++st) {
            const int rbase = (st * 16 + lr) * 64;
            bf16x8 kh0 = *(const bf16x8*)&kb[rbase + ((quad    ) ^ sw) * 8];
            bf16x8 kh1 = *(const bf16x8*)&kb[rbase + ((quad + 4) ^ sw) * 8];
            bf16x8 kl0 = *(const bf16x8*)&kb[4096 + rbase + ((quad    ) ^ sw) * 8];
            bf16x8 kl1 = *(const bf16x8*)&kb[4096 + rbase + ((quad + 4) ^ sw) * 8];
            sk4[st] = *(const f32x4*)&skn[(size_t)bh * SS + kbase + st * 16 + quad * 4];
            f32x4 a = (f32x4){0.f, 0.f, 0.f, 0.f};
            a = MFMA16(kh0, qh[0], a);
            a = MFMA16(kh1, qh[1], a);
            a = MFMA16(kl0, qh[0], a);
            a = MFMA16(kl1, qh[1], a);
            a = MFMA16(kh0, ql[0], a);
            a = MFMA16(kh1, ql[1], a);
            acc[st] = a;
        }
        // ---- V fragments (global; issue early to overlap softmax VALU) ----
        bf16x8 vf[4][2];
        #pragma unroll
        for (int nd = 0; nd < 4; ++nd)
            #pragma unroll
            for (int kk = 0; kk < 2; ++kk)
                vf[nd][kk] = *(const bf16x8*)&vt[((size_t)bh * DD + nd * 16 + lr) * SS
                                                 + kbase + kk * 32 + quad * 8];
        // ---- softmax (exp2 domain, in-place over acc) ----
        unsigned short* myP = Ps[p][w];
        float mx = -INFINITY;
        #pragma unroll
        for (int st = 0; st < 4; ++st)
            #pragma unroll
            for (int r = 0; r < 4; ++r) {
                float qk = acc[st][r];
                float d = sqe + sk4[st][r] - 2.f * qk;
                float s = qk * qk * cscale * RCPF(d);
                acc[st][r] = s;
                mx = fmaxf(mx, s);
            }
        mx = fmaxf(mx, __shfl_xor(mx, 16));
        mx = fmaxf(mx, __shfl_xor(mx, 32));
        float mnew = fmaxf(m_r, mx);
        float aa = EXP2(m_r - mnew);
        m_r = mnew;
        float rs = 0.f;
        #pragma unroll
        for (int st = 0; st < 4; ++st)
            #pragma unroll
            for (int r = 0; r < 4; ++r) {
                float e = EXP2(acc[st][r] - mnew);
                acc[st][r] = e;
                rs += e;
            }
        rs += __shfl_xor(rs, 16);
        rs += __shfl_xor(rs, 32);
        l_r = l_r * aa + rs;
        #pragma unroll
        for (int st = 0; st < 4; ++st) {
            short4v pv;
            pv[0] = (short)f2bf(acc[st][0]);
            pv[1] = (short)f2bf(acc[st][1]);
            pv[2] = (short)f2bf(acc[st][2]);
            pv[3] = (short)f2bf(acc[st][3]);
            *(short4v*)&myP[lr * 68 + st * 16 + quad * 4] = pv;
        }
        float al_[4];
        #pragma unroll
        for (int r = 0; r < 4; ++r) al_[r] = __shfl(aa, quad * 4 + r);
        #pragma unroll
        for (int nd = 0; nd < 4; ++nd)
            #pragma unroll
            for (int r = 0; r < 4; ++r)
                O[nd][r] *= al_[r];
        // ---- PV: A = P from LDS, B = V^T ----
        bf16x8 pf[2];
        #pragma unroll
        for (int kk = 0; kk < 2; ++kk)
            pf[kk] = *(const bf16x8*)&myP[lr * 68 + kk * 32 + quad * 8];
        #pragma unroll
        for (int nd = 0; nd < 4; ++nd)
            #pragma unroll
            for (int kk = 0; kk < 2; ++kk)
                O[nd] = MFMA16(pf[kk], vf[nd][kk], O[nd]);
    }
    // ---- epilogue: write fp16 partial O + (m,l) ----
    if (quad == 0)
        mlpart[(size_t)z * RR + (size_t)bh * SS + row0 + lr] = make_float2(m_r, l_r);
    #pragma unroll
    for (int r = 0; r < 4; ++r) {
        size_t rowg = (size_t)bh * SS + row0 + quad * 4 + r;
        #pragma unroll
        for (int nd = 0; nd < 4; ++nd)
            Opart[((size_t)z * RR + rowg) * DD + nd * 16 + lr] =
                __float2half(O[nd][r]);
    }
}

// merge the two K-split halves: standard online-softmax combine, write ctx hi/lo
__global__ __launch_bounds__(256) void combine_attn(
        const __half* __restrict__ Opart, const float2* __restrict__ mlpart,
        unsigned short* __restrict__ ctxhi, unsigned short* __restrict__ ctxlo) {
    int tid = blockIdx.x * 256 + threadIdx.x;
    int row = tid >> 4, c4 = (tid & 15) * 4;
    float2 ml0 = mlpart[row];
    float2 ml1 = mlpart[RR + row];
    float ms = fmaxf(ml0.x, ml1.x);
    float a0 = EXP2(ml0.x - ms), a1 = EXP2(ml1.x - ms);
    float inv = RCPF(ml0.y * a0 + ml1.y * a1);
    a0 *= inv; a1 *= inv;
    const __half* p0 = Opart + (size_t)row * DD + c4;
    const __half* p1 = p0 + (size_t)RR * DD;
    int bh = row >> 11, s = row & (SS - 1);
    int b = bh >> 4, h = bh & 15;
    size_t idx = ((size_t)b * SS + s) * EE + h * DD + c4;
    ushort4 hv, lv;
    unsigned short* hp = (unsigned short*)&hv;
    unsigned short* lp = (unsigned short*)&lv;
    #pragma unroll
    for (int j = 0; j < 4; ++j) {
        float o = __half2float(p0[j]) * a0 + __half2float(p1[j]) * a1;
        unsigned short hh = f2bf(o);
        hp[j] = hh;
        lp[j] = f2bf(o - bf2f(hh));
    }
    *(ushort4*)&ctxhi[idx] = hv;
    *(ushort4*)&ctxlo[idx] = lv;
}

extern "C" void kernel_launch(void* const* d_in, const int* in_sizes, int n_in,
                              void* d_out, int out_size, void* d_ws, size_t ws_size,
                              hipStream_t stream) {
    const float* x     = (const float*)d_in[0];
    const float* Wq    = (const float*)d_in[1];
    const float* bq    = (const float*)d_in[2];
    const float* Wk    = (const float*)d_in[3];
    const float* bk    = (const float*)d_in[4];
    const float* Wv    = (const float*)d_in[5];
    const float* bv    = (const float*)d_in[6];
    const float* Wo    = (const float*)d_in[7];
    const float* bo    = (const float*)d_in[8];
    const float* alpha = (const float*)d_in[9];
    float* out = (float*)d_out;
    char* ws = (char*)d_ws;

    const int M = BB * SS;                 // 4096
    const size_t MB = 1u << 20;
    // layout (MB offsets); aliases safe per pipeline order:
    unsigned short* xhi  = (unsigned short*)(ws + 0 * MB);   // later: ctxhi
    unsigned short* xlo  = (unsigned short*)(ws + 8 * MB);   // later: ctxlo
    unsigned short* Whi  = (unsigned short*)(ws + 16 * MB);  // 6 MB (qkv concat)
    unsigned short* Wlo  = (unsigned short*)(ws + 22 * MB);  // 6 MB
    unsigned short* vt   = (unsigned short*)(ws + 16 * MB);  // 8 MB, reuses dead W
    float2* mlpart       = (float2*)(ws + 24 * MB);          // 1 MB, dead Wlo tail
    unsigned short* Wohi = (unsigned short*)(ws + 28 * MB);
    unsigned short* Wolo = (unsigned short*)(ws + 30 * MB);
    unsigned short* qhi  = (unsigned short*)(ws + 32 * MB);
    unsigned short* qlo  = (unsigned short*)(ws + 40 * MB);
    unsigned short* khi  = (unsigned short*)(ws + 48 * MB);
    unsigned short* klo  = (unsigned short*)(ws + 56 * MB);
    unsigned short* v_sd = (unsigned short*)(ws + 64 * MB);  // dead after transpose
    __half* Opart        = (__half*)(ws + 64 * MB);          // 16 MB (reuses v_sd)
    float* sqn = (float*)(ws + 80 * MB);
    float* skn = (float*)(ws + 80 * MB + 256 * 1024);
    unsigned short* ctxhi = xhi;
    unsigned short* ctxlo = xlo;

    const int nX = M * EE / 4, nW = EE * EE / 4;
    split_f32<<<nX / 256, 256, 0, stream>>>(x, xhi, xlo, nX);
    split_w4<<<dim3(nW / 256, 4), 256, 0, stream>>>(Wq, Wk, Wv, Wo,
                                                    Whi, Wlo, Wohi, Wolo);

    gemm3p<1><<<dim3(3 * EE / 128, M / 128), 256, 0, stream>>>(
        xhi, xlo, Whi, Wlo, bq, bk, bv, nullptr,
        qhi, qlo, khi, klo, v_sd, sqn, skn, M, 3 * EE, EE);

    transpose_v<<<dim3(SS / 64, BB * HH), 256, 0, stream>>>(v_sd, vt);

    yat_attn_mfma<<<dim3(SS / 64, BB * HH, 2), 256, 0, stream>>>(
        qhi, qlo, khi, klo, vt, sqn, skn, alpha, Opart, mlpart);

    combine_attn<<<RR * 16 / 256, 256, 0, stream>>>(Opart, mlpart, ctxhi, ctxlo);

    gemm3p<0><<<dim3(EE / 128, M / 128), 256, 0, stream>>>(
        ctxhi, ctxlo, Wohi, Wolo, bo, nullptr, nullptr, out,
        nullptr, nullptr, nullptr, nullptr, nullptr, nullptr, nullptr, M, EE, EE);
}

// Round 11
// 358.086 us; speedup vs baseline: 1.1843x; 1.0655x over previous
//
#include <hip/hip_runtime.h>
#include <hip/hip_fp16.h>
#include <math.h>

#define BB 2
#define SS 2048
#define EE 1024
#define HH 16
#define DD 64
#define YAT_EPS 1e-5f
#define RR (BB * HH * SS)   // 65536 attention rows

typedef __attribute__((ext_vector_type(8))) short bf16x8;
typedef __attribute__((ext_vector_type(4))) short short4v;
typedef __attribute__((ext_vector_type(4))) float f32x4;
#define MFMA16(a, b, c) __builtin_amdgcn_mfma_f32_16x16x32_bf16((a), (b), (c), 0, 0, 0)

#if __has_builtin(__builtin_amdgcn_exp2f)
#define EXP2(x) __builtin_amdgcn_exp2f(x)
#else
#define EXP2(x) exp2f(x)
#endif
#if __has_builtin(__builtin_amdgcn_rcpf)
#define RCPF(x) __builtin_amdgcn_rcpf(x)
#else
#define RCPF(x) (1.0f / (x))
#endif

__device__ __forceinline__ unsigned short f2bf(float x) {
    unsigned int u = __float_as_uint(x);
    u += 0x7FFFu + ((u >> 16) & 1u);   // RNE
    return (unsigned short)(u >> 16);
}
__device__ __forceinline__ float bf2f(unsigned short h) {
    return __uint_as_float(((unsigned int)h) << 16);
}
// truncating fp32->bf16 (1 op; P in [0,1], bias ~0.1% — renorm-safe)
__device__ __forceinline__ short f2bf_t(float x) {
    return (short)(__float_as_uint(x) >> 16);
}

__device__ __forceinline__ void async_ld16(void* lds, const void* g) {
    __builtin_amdgcn_global_load_lds(
        (const __attribute__((address_space(1))) unsigned int*)g,
        (__attribute__((address_space(3))) unsigned int*)lds, 16, 0, 0);
}

// fp32 -> bf16 hi/lo split (grid covers n/4 float4s exactly)
__global__ __launch_bounds__(256) void split_f32(const float* __restrict__ in,
                                                 unsigned short* __restrict__ hi,
                                                 unsigned short* __restrict__ lo,
                                                 int n4) {
    int i = blockIdx.x * 256 + threadIdx.x;
    if (i >= n4) return;
    float4 v = ((const float4*)in)[i];
    ushort4 h, l;
    h.x = f2bf(v.x); l.x = f2bf(v.x - bf2f(h.x));
    h.y = f2bf(v.y); l.y = f2bf(v.y - bf2f(h.y));
    h.z = f2bf(v.z); l.z = f2bf(v.z - bf2f(h.z));
    h.w = f2bf(v.w); l.w = f2bf(v.w - bf2f(h.w));
    ((ushort4*)hi)[i] = h;
    ((ushort4*)lo)[i] = l;
}

// fused hi/lo split of the four weight matrices; lo only needed for Wq,Wk
// (V is consumed bf16; O-proj runs plain bf16 — error ~6e-4, negligible)
__global__ __launch_bounds__(256) void split_w4(
        const float* __restrict__ Wq, const float* __restrict__ Wk,
        const float* __restrict__ Wv, const float* __restrict__ Wo,
        unsigned short* __restrict__ Whi, unsigned short* __restrict__ Wlo,
        unsigned short* __restrict__ Wohi) {
    int i = blockIdx.x * 256 + threadIdx.x;      // < EE*EE/4
    int y = blockIdx.y;
    const float* src = y == 0 ? Wq : y == 1 ? Wk : y == 2 ? Wv : Wo;
    unsigned short* hi = y < 3 ? Whi + (size_t)y * EE * EE : Wohi;
    float4 v = ((const float4*)src)[i];
    ushort4 h;
    h.x = f2bf(v.x); h.y = f2bf(v.y); h.z = f2bf(v.z); h.w = f2bf(v.w);
    ((ushort4*)hi)[i] = h;
    if (y < 2) {
        unsigned short* lo = Wlo + (size_t)y * EE * EE;
        ushort4 l;
        l.x = f2bf(v.x - bf2f(h.x));
        l.y = f2bf(v.y - bf2f(h.y));
        l.z = f2bf(v.z - bf2f(h.z));
        l.w = f2bf(v.w - bf2f(h.w));
        ((ushort4*)lo)[i] = l;
    }
}

// bf16 MFMA GEMM, PASSES=3 (hi/lo Markidis) or 1 (plain bf16).
// C[M,N] = A[M,K] @ B[N,K]^T + bias.
// MODE 0: fp32 out + bias(bq).
// MODE 1: q/k epilogue (N=2048): bf16 hi(+lo for q) [B,H,S,D] + fp32 norms.
// MODE 2: v epilogue (N=1024): bf16 [B,H,S,D], bias in bv.
template <int MODE, int PASSES>
__global__ __launch_bounds__(256, 2) void gemm3p(
        const unsigned short* __restrict__ Ahi, const unsigned short* __restrict__ Alo,
        const unsigned short* __restrict__ Bhi, const unsigned short* __restrict__ Blo,
        const float* __restrict__ bq, const float* __restrict__ bk,
        const float* __restrict__ bv,
        float* __restrict__ Cf,
        unsigned short* __restrict__ qhi, unsigned short* __restrict__ qlo,
        unsigned short* __restrict__ khi,
        unsigned short* __restrict__ v_sd,
        float* __restrict__ sqn, float* __restrict__ skn,
        int M, int N, int K) {
    __shared__ __align__(16) unsigned short LA_hi[128 * 32];
    __shared__ __align__(16) unsigned short LA_lo[128 * 32];
    __shared__ __align__(16) unsigned short LB_hi[128 * 32];
    __shared__ __align__(16) unsigned short LB_lo[128 * 32];

    const int t = threadIdx.x;
    const int w = t >> 6, lane = t & 63;
    const int quad = lane >> 4, lr = lane & 15;
    const int wy = w & 1, wx = w >> 1;
    const int m0 = blockIdx.y * 128, n0 = blockIdx.x * 128;

    const unsigned short* gsrc = nullptr;
    unsigned short* ldst = nullptr;
    if (w == 0)      { gsrc = Ahi + (size_t)m0 * K; ldst = LA_hi; }
    else if (w == 2) { gsrc = Bhi + (size_t)n0 * K; ldst = LB_hi; }
    else if (PASSES == 3 && w == 1) { gsrc = Alo + (size_t)m0 * K; ldst = LA_lo; }
    else if (PASSES == 3 && w == 3) { gsrc = Blo + (size_t)n0 * K; ldst = LB_lo; }
    const unsigned short* gl = gsrc ? gsrc + (size_t)(lane >> 2) * K + (lane & 3) * 8
                                    : nullptr;

    f32x4 acc[4][4];
    #pragma unroll
    for (int i = 0; i < 4; ++i)
        #pragma unroll
        for (int j = 0; j < 4; ++j)
            acc[i][j] = (f32x4){0.f, 0.f, 0.f, 0.f};

    for (int k0 = 0; k0 < K; k0 += 32) {
        __syncthreads();
        if (gl) {
            #pragma unroll
            for (int i = 0; i < 8; ++i)
                async_ld16(ldst + i * 512, gl + (size_t)i * 16 * K + k0);
        }
        __syncthreads();
        bf16x8 ah[4], al[4], bh_[4], bl_[4];
        #pragma unroll
        for (int i = 0; i < 4; ++i) {
            ah[i]  = *(const bf16x8*)&LA_hi[(wy * 64 + i * 16 + lr) * 32 + quad * 8];
            bh_[i] = *(const bf16x8*)&LB_hi[(wx * 64 + i * 16 + lr) * 32 + quad * 8];
            if (PASSES == 3) {
                al[i]  = *(const bf16x8*)&LA_lo[(wy * 64 + i * 16 + lr) * 32 + quad * 8];
                bl_[i] = *(const bf16x8*)&LB_lo[(wx * 64 + i * 16 + lr) * 32 + quad * 8];
            }
        }
        #pragma unroll
        for (int mg = 0; mg < 4; ++mg)
            #pragma unroll
            for (int ns = 0; ns < 4; ++ns) {
                f32x4 a = acc[mg][ns];
                a = MFMA16(ah[mg], bh_[ns], a);
                if (PASSES == 3) {
                    a = MFMA16(ah[mg], bl_[ns], a);
                    a = MFMA16(al[mg], bh_[ns], a);
                }
                acc[mg][ns] = a;
            }
    }

    const int ng = n0 + wx * 64;
    if (MODE == 0) {
        float bias_v[4];
        #pragma unroll
        for (int ns = 0; ns < 4; ++ns) bias_v[ns] = bq[ng + ns * 16 + lr];
        #pragma unroll
        for (int mg = 0; mg < 4; ++mg)
            #pragma unroll
            for (int r = 0; r < 4; ++r) {
                int m = m0 + wy * 64 + mg * 16 + quad * 4 + r;
                #pragma unroll
                for (int ns = 0; ns < 4; ++ns)
                    Cf[(size_t)m * N + ng + ns * 16 + lr] = acc[mg][ns][r] + bias_v[ns];
            }
    } else {
        const int path = MODE == 1 ? (ng >> 10) : 2;   // 0=q 1=k 2=v
        const int c = MODE == 1 ? (ng & 1023) : ng;
        const int h = c >> 6;
        const float* bias = path == 0 ? bq : path == 1 ? bk : bv;
        unsigned short* hi_p = path == 0 ? qhi : path == 1 ? khi : v_sd;
        float* nrm = path == 0 ? sqn : skn;
        float bias_v[4];
        #pragma unroll
        for (int ns = 0; ns < 4; ++ns) bias_v[ns] = bias[c + ns * 16 + lr];
        #pragma unroll
        for (int mg = 0; mg < 4; ++mg)
            #pragma unroll
            for (int r = 0; r < 4; ++r) {
                int m = m0 + wy * 64 + mg * 16 + quad * 4 + r;
                int b = m >> 11, s = m & (SS - 1);
                size_t base = ((size_t)(b * HH + h) * SS + s) * DD;
                float v4[4];
                #pragma unroll
                for (int ns = 0; ns < 4; ++ns) v4[ns] = acc[mg][ns][r] + bias_v[ns];
                if (path < 2) {
                    float pn = v4[0] * v4[0] + v4[1] * v4[1] + v4[2] * v4[2] + v4[3] * v4[3];
                    #pragma unroll
                    for (int off = 1; off < 16; off <<= 1) pn += __shfl_xor(pn, off);
                    if (lr == 0) nrm[(size_t)(b * HH + h) * SS + s] = pn;
                    #pragma unroll
                    for (int ns = 0; ns < 4; ++ns) {
                        unsigned short hv = f2bf(v4[ns]);
                        hi_p[base + ns * 16 + lr] = hv;
                        if (path == 0)
                            qlo[base + ns * 16 + lr] = f2bf(v4[ns] - bf2f(hv));
                    }
                } else {
                    #pragma unroll
                    for (int ns = 0; ns < 4; ++ns)
                        hi_p[base + ns * 16 + lr] = f2bf(v4[ns]);
                }
            }
    }
}

// [bh][s][d] -> [bh][d][s] bf16 transpose, 64x64 LDS tiles
__global__ __launch_bounds__(256) void transpose_v(const unsigned short* __restrict__ v_sd,
                                                   unsigned short* __restrict__ vt) {
    __shared__ unsigned short T[64][65];
    const int t = threadIdx.x;
    const int bh = blockIdx.y, s0 = blockIdx.x * 64;
    {
        int sl = t >> 2, d4 = (t & 3) * 16;
        const unsigned short* src = &v_sd[((size_t)bh * SS + s0 + sl) * DD + d4];
        bf16x8 a = *(const bf16x8*)src;
        bf16x8 b = *(const bf16x8*)(src + 8);
        #pragma unroll
        for (int j = 0; j < 8; ++j) {
            T[sl][d4 + j] = (unsigned short)a[j];
            T[sl][d4 + 8 + j] = (unsigned short)b[j];
        }
    }
    __syncthreads();
    {
        int dl = t >> 2, s4 = (t & 3) * 16;
        bf16x8 a, b;
        #pragma unroll
        for (int j = 0; j < 8; ++j) {
            a[j] = (short)T[s4 + j][dl];
            b[j] = (short)T[s4 + 8 + j][dl];
        }
        unsigned short* dst = &vt[((size_t)bh * DD + dl) * SS + s0 + s4];
        *(bf16x8*)dst = a;
        *(bf16x8*)(dst + 8) = b;
    }
}

// MFMA flash attention v5: K staged in LDS as bf16-HI ONLY (2-pass QK:
// qk = kh·(qh+ql); missing q·kl term ~9e-3 absolute — inside error budget).
// Halves K LDS (16KB dbuf) and QK MFMA (4/st): LDS 33.8KB -> 4 blocks/CU,
// per-iter issue work cut ~25%. Truncating P pack (1 op/elem).
__global__ __launch_bounds__(256, 3) void yat_attn_mfma(
        const unsigned short* __restrict__ qhi, const unsigned short* __restrict__ qlo,
        const unsigned short* __restrict__ khi,
        const unsigned short* __restrict__ vt,
        const float* __restrict__ sqn, const float* __restrict__ skn,
        const float* __restrict__ alphap,
        __half* __restrict__ Opart, float2* __restrict__ mlpart) {
    __shared__ __align__(16) unsigned short Ks[2][4096];        // [dbuf] khi, 16KB
    __shared__ __align__(16) unsigned short Ps[2][4][16 * 68];  // [dbuf][wave] 17.4KB

    const int t = threadIdx.x;
    const int w = t >> 6, lane = t & 63;
    const int quad = lane >> 4, lr = lane & 15;
    const int qt = blockIdx.x, bh = blockIdx.y, z = blockIdx.z;
    const int row0 = qt * 64 + w * 16;
    const float cscale = powf(sqrtf((float)DD) / log1pf((float)DD), alphap[0])
                         * 1.4426950408889634f;

    // persistent Q fragments (B-operand: lane holds q-col = lr)
    bf16x8 qh[2], ql[2];
    #pragma unroll
    for (int kd = 0; kd < 2; ++kd) {
        size_t o = ((size_t)bh * SS + row0 + lr) * DD + kd * 32 + quad * 8;
        qh[kd] = *(const bf16x8*)&qhi[o];
        ql[kd] = *(const bf16x8*)&qlo[o];
    }
    const float sqe = sqn[(size_t)bh * SS + row0 + lr] + YAT_EPS;

    // staging: wave w stages rows [w*16,w*16+16) of khi; XOR-swizzled chunks
    const int lrow = lane >> 3;
    const int lofs = lrow * 64 + (((lane & 7) ^ (lrow & 7)) << 3);

    float m_r = -INFINITY, l_r = 0.f;
    f32x4 O[4];
    #pragma unroll
    for (int nd = 0; nd < 4; ++nd) O[nd] = (f32x4){0.f, 0.f, 0.f, 0.f};

    const int kt0 = z * 16;
    {   // prologue: stage tile 0 into buf 0
        const size_t gbase = ((size_t)bh * SS + kt0 * 64 + w * 16) * 64 + lofs;
        #pragma unroll
        for (int i2 = 0; i2 < 2; ++i2)
            async_ld16(&Ks[0][w * 1024 + i2 * 512], khi + gbase + i2 * 512);
    }

    for (int it = 0; it < 16; ++it) {
        const int kt = kt0 + it;
        const int p = it & 1;
        const int kbase = kt * 64;
        __syncthreads();   // drains async stage of buf[p]
        if (it < 15) {
            const size_t gbase = ((size_t)bh * SS + (kt + 1) * 64 + w * 16) * 64 + lofs;
            #pragma unroll
            for (int i2 = 0; i2 < 2; ++i2)
                async_ld16(&Ks[p ^ 1][w * 1024 + i2 * 512], khi + gbase + i2 * 512);
        }
        // ---- QK'^T = K.(qh+ql)^T from LDS (2-pass) ----
        f32x4 acc[4];
        f32x4 sk4[4];
        const unsigned short* kb = Ks[p];
        const int sw = lr & 7;
        #pragma unroll
        for (int st = 0; st < 4; ++st) {
            const int rbase = (st * 16 + lr) * 64;
            bf16x8 kh0 = *(const bf16x8*)&kb[rbase + ((quad    ) ^ sw) * 8];
            bf16x8 kh1 = *(const bf16x8*)&kb[rbase + ((quad + 4) ^ sw) * 8];
            sk4[st] = *(const f32x4*)&skn[(size_t)bh * SS + kbase + st * 16 + quad * 4];
            f32x4 a = (f32x4){0.f, 0.f, 0.f, 0.f};
            a = MFMA16(kh0, qh[0], a);
            a = MFMA16(kh1, qh[1], a);
            a = MFMA16(kh0, ql[0], a);
            a = MFMA16(kh1, ql[1], a);
            acc[st] = a;
        }
        // ---- V fragments (global; issue early) ----
        bf16x8 vf[4][2];
        #pragma unroll
        for (int nd = 0; nd < 4; ++nd)
            #pragma unroll
            for (int kk = 0; kk < 2; ++kk)
                vf[nd][kk] = *(const bf16x8*)&vt[((size_t)bh * DD + nd * 16 + lr) * SS
                                                 + kbase + kk * 32 + quad * 8];
        // ---- softmax (exp2 domain, in-place over acc) ----
        unsigned short* myP = Ps[p][w];
        float mx = -INFINITY;
        #pragma unroll
        for (int st = 0; st < 4; ++st)
            #pragma unroll
            for (int r = 0; r < 4; ++r) {
                float qk = acc[st][r];
                float d = sqe + sk4[st][r] - 2.f * qk;
                float s = qk * qk * cscale * RCPF(d);
                acc[st][r] = s;
                mx = fmaxf(mx, s);
            }
        mx = fmaxf(mx, __shfl_xor(mx, 16));
        mx = fmaxf(mx, __shfl_xor(mx, 32));
        float mnew = fmaxf(m_r, mx);
        float aa = EXP2(m_r - mnew);
        m_r = mnew;
        float rs = 0.f;
        #pragma unroll
        for (int st = 0; st < 4; ++st)
            #pragma unroll
            for (int r = 0; r < 4; ++r) {
                float e = EXP2(acc[st][r] - mnew);
                acc[st][r] = e;
                rs += e;
            }
        rs += __shfl_xor(rs, 16);
        rs += __shfl_xor(rs, 32);
        l_r = l_r * aa + rs;
        #pragma unroll
        for (int st = 0; st < 4; ++st) {
            short4v pv;
            pv[0] = f2bf_t(acc[st][0]);
            pv[1] = f2bf_t(acc[st][1]);
            pv[2] = f2bf_t(acc[st][2]);
            pv[3] = f2bf_t(acc[st][3]);
            *(short4v*)&myP[lr * 68 + st * 16 + quad * 4] = pv;
        }
        float al_[4];
        #pragma unroll
        for (int r = 0; r < 4; ++r) al_[r] = __shfl(aa, quad * 4 + r);
        #pragma unroll
        for (int nd = 0; nd < 4; ++nd)
            #pragma unroll
            for (int r = 0; r < 4; ++r)
                O[nd][r] *= al_[r];
        // ---- PV: A = P from LDS, B = V^T ----
        bf16x8 pf[2];
        #pragma unroll
        for (int kk = 0; kk < 2; ++kk)
            pf[kk] = *(const bf16x8*)&myP[lr * 68 + kk * 32 + quad * 8];
        #pragma unroll
        for (int nd = 0; nd < 4; ++nd)
            #pragma unroll
            for (int kk = 0; kk < 2; ++kk)
                O[nd] = MFMA16(pf[kk], vf[nd][kk], O[nd]);
    }
    // ---- epilogue: write fp16 partial O + (m,l) ----
    if (quad == 0)
        mlpart[(size_t)z * RR + (size_t)bh * SS + row0 + lr] = make_float2(m_r, l_r);
    #pragma unroll
    for (int r = 0; r < 4; ++r) {
        size_t rowg = (size_t)bh * SS + row0 + quad * 4 + r;
        #pragma unroll
        for (int nd = 0; nd < 4; ++nd)
            Opart[((size_t)z * RR + rowg) * DD + nd * 16 + lr] =
                __float2half(O[nd][r]);
    }
}

// merge K-split halves; write ctx bf16 (hi only — O-proj is plain bf16)
__global__ __launch_bounds__(256) void combine_attn(
        const __half* __restrict__ Opart, const float2* __restrict__ mlpart,
        unsigned short* __restrict__ ctxhi) {
    int tid = blockIdx.x * 256 + threadIdx.x;
    int row = tid >> 4, c4 = (tid & 15) * 4;
    float2 ml0 = mlpart[row];
    float2 ml1 = mlpart[RR + row];
    float ms = fmaxf(ml0.x, ml1.x);
    float a0 = EXP2(ml0.x - ms), a1 = EXP2(ml1.x - ms);
    float inv = RCPF(ml0.y * a0 + ml1.y * a1);
    a0 *= inv; a1 *= inv;
    const __half* p0 = Opart + (size_t)row * DD + c4;
    const __half* p1 = p0 + (size_t)RR * DD;
    int bh = row >> 11, s = row & (SS - 1);
    int b = bh >> 4, h = bh & 15;
    size_t idx = ((size_t)b * SS + s) * EE + h * DD + c4;
    ushort4 hv;
    unsigned short* hp = (unsigned short*)&hv;
    #pragma unroll
    for (int j = 0; j < 4; ++j) {
        float o = __half2float(p0[j]) * a0 + __half2float(p1[j]) * a1;
        hp[j] = f2bf(o);
    }
    *(ushort4*)&ctxhi[idx] = hv;
}

extern "C" void kernel_launch(void* const* d_in, const int* in_sizes, int n_in,
                              void* d_out, int out_size, void* d_ws, size_t ws_size,
                              hipStream_t stream) {
    const float* x     = (const float*)d_in[0];
    const float* Wq    = (const float*)d_in[1];
    const float* bq    = (const float*)d_in[2];
    const float* Wk    = (const float*)d_in[3];
    const float* bk    = (const float*)d_in[4];
    const float* Wv    = (const float*)d_in[5];
    const float* bv    = (const float*)d_in[6];
    const float* Wo    = (const float*)d_in[7];
    const float* bo    = (const float*)d_in[8];
    const float* alpha = (const float*)d_in[9];
    float* out = (float*)d_out;
    char* ws = (char*)d_ws;

    const int M = BB * SS;                 // 4096
    const size_t MB = 1u << 20;
    unsigned short* xhi  = (unsigned short*)(ws + 0 * MB);   // later: ctxhi
    unsigned short* xlo  = (unsigned short*)(ws + 8 * MB);
    unsigned short* Whi  = (unsigned short*)(ws + 16 * MB);  // 6 MB (qkv concat)
    unsigned short* Wlo  = (unsigned short*)(ws + 22 * MB);  // 4 MB used (q,k)
    unsigned short* vt   = (unsigned short*)(ws + 16 * MB);  // reuses dead Whi area
    float2* mlpart       = (float2*)(ws + 24 * MB);          // 1 MB
    unsigned short* Wohi = (unsigned short*)(ws + 28 * MB);
    unsigned short* qhi  = (unsigned short*)(ws + 32 * MB);
    unsigned short* qlo  = (unsigned short*)(ws + 40 * MB);
    unsigned short* khi  = (unsigned short*)(ws + 48 * MB);
    unsigned short* v_sd = (unsigned short*)(ws + 64 * MB);  // dead after transpose
    __half* Opart        = (__half*)(ws + 64 * MB);          // 16 MB (reuses v_sd)
    float* sqn = (float*)(ws + 80 * MB);
    float* skn = (float*)(ws + 80 * MB + 256 * 1024);
    unsigned short* ctxhi = xhi;

    const int nX = M * EE / 4, nW = EE * EE / 4;
    split_f32<<<nX / 256, 256, 0, stream>>>(x, xhi, xlo, nX);
    split_w4<<<dim3(nW / 256, 4), 256, 0, stream>>>(Wq, Wk, Wv, Wo, Whi, Wlo, Wohi);

    // Q/K projections: 3-pass (K=1024 — 2-pass would inject ~0.03 into q/k)
    gemm3p<1, 3><<<dim3(2 * EE / 128, M / 128), 256, 0, stream>>>(
        xhi, xlo, Whi, Wlo, bq, bk, nullptr, nullptr,
        qhi, qlo, khi, nullptr, sqn, skn, M, 2 * EE, EE);
    // V projection: plain bf16 (consumed as bf16 anyway)
    gemm3p<2, 1><<<dim3(EE / 128, M / 128), 256, 0, stream>>>(
        xhi, nullptr, Whi + 2 * (size_t)EE * EE, nullptr, nullptr, nullptr, bv, nullptr,
        nullptr, nullptr, nullptr, v_sd, nullptr, nullptr, M, EE, EE);

    transpose_v<<<dim3(SS / 64, BB * HH), 256, 0, stream>>>(v_sd, vt);

    yat_attn_mfma<<<dim3(SS / 64, BB * HH, 2), 256, 0, stream>>>(
        qhi, qlo, khi, vt, sqn, skn, alpha, Opart, mlpart);

    combine_attn<<<RR * 16 / 256, 256, 0, stream>>>(Opart, mlpart, ctxhi);

    // O projection: plain bf16 (error ~6e-4 ≪ threshold)
    gemm3p<0, 1><<<dim3(EE / 128, M / 128), 256, 0, stream>>>(
        ctxhi, nullptr, Wohi, nullptr, bo, nullptr, nullptr, out,
        nullptr, nullptr, nullptr, nullptr, nullptr, nullptr, M, EE, EE);
}